// Round 4
// baseline (95.640 us; speedup 1.0000x reference)
//
#include <hip/hip_runtime.h>

// R14 — 3 dispatches, no device fences, no sort stage:
//   gram     (33 blk x 512) : blocks 0-31 = MFMA f16 Gram in ORIGINAL row
//                             order (inline fp32->fp16 convert), 32x32/wave;
//                             block 32 = label ranks + sorted labels
//                             (concurrent with tiles -> free)
//   main     (256 blk)      : block b <-> orig rows (2b,2b+1); norms from G
//                             diag; e scattered to sorted position by rank;
//                             unchanged wave scans + exact binsearch denom
//   finalize (1 blk)        : reduce 256 partials
// Rationale: R8->R12 calibrated ~5us per dispatch removed; kernel interiors
// are ~2-4us each (all L2-resident), so only dispatch count matters.
// Measured regressions to avoid: fused per-block G-rows-in-main (+8us, R12:
// 128MB redundant L3 traffic on main's critical path), ticket+threadfence
// finalize (+3us, R11), 2-kernel merge with PERMUTED-read Gram (+5.5us, R9
// — this version keeps all Gram/main reads coalesced), cooperative
// grid.sync (+90us, R10), fp16 phase-1 in main (+4us, R6).

#define N 512          // n = 2*B
#define B 256
#define D 512
#define NT 512         // block size everywhere
#define NBLK (N / 2)   // 256 main blocks, 2 rows each

// ws layout (float offsets)
#define WS_SL    0                    // [N] sorted labels ascending
#define WS_RK    512                  // [N] int rank of orig row j
#define WS_PART  1024                 // [NBLK] per-block partial sums
#define WS_G     2048                 // [N*N] fp32 Gram, ORIGINAL order (1 MB)

typedef _Float16 half8_t  __attribute__((ext_vector_type(8)));
typedef float    f32x4    __attribute__((ext_vector_type(4)));

static __device__ __forceinline__ half8_t cvt8(const float* p) {
    const float4 u = ((const float4*)p)[0];
    const float4 v = ((const float4*)p)[1];
    half8_t h;
    h[0] = (_Float16)u.x; h[1] = (_Float16)u.y;
    h[2] = (_Float16)u.z; h[3] = (_Float16)u.w;
    h[4] = (_Float16)v.x; h[5] = (_Float16)v.y;
    h[6] = (_Float16)v.z; h[7] = (_Float16)v.w;
    return h;
}

// ---- kernel 1 (grid 33 x 512thr): Gram (orig order) + rank side-block ----
// Tiles: wid = blk*8 + wave in [0,256); 32x32 tile/wave, 2x2 accumulators.
// Rows ti*32+m and +16 stay within one input half (256 = 8*32). Same MFMA
// k-order as R13 -> bit-identical G. C/D layout (verified): col=lane&15,
// row=quad*4+reg.
__global__ __launch_bounds__(NT) void gram_kernel(
    const float* __restrict__ wt, const float* __restrict__ mt,
    const float* __restrict__ lwt, const float* __restrict__ lmt,
    float* __restrict__ ws)
{
    const int t = threadIdx.x;

    if (blockIdx.x == 32) {
        // ---- rank block: ranks + sorted labels (concurrent with tiles) ----
        __shared__ float slab[N];
        slab[t] = (t < B) ? lwt[t] : lmt[t - B];
        __syncthreads();
        const float lj = slab[t];
        int r = 0;
        const float4* s4 = (const float4*)slab;
        #pragma unroll 4
        for (int x4 = 0; x4 < N / 4; ++x4) {
            const float4 v = s4[x4];          // broadcast read, conflict-free
            const int xb = x4 * 4;
            r += (v.x < lj || (v.x == lj && xb + 0 < t)) ? 1 : 0;
            r += (v.y < lj || (v.y == lj && xb + 1 < t)) ? 1 : 0;
            r += (v.z < lj || (v.z == lj && xb + 2 < t)) ? 1 : 0;
            r += (v.w < lj || (v.w == lj && xb + 3 < t)) ? 1 : 0;
        }
        ws[WS_SL + r] = lj;                   // bijective scatter
        ((int*)ws)[WS_RK + t] = r;
        return;
    }

    const int lane = t & 63;
    const int wid  = blockIdx.x * 8 + (t >> 6);            // 0..255
    const int ti = wid >> 4, tj = wid & 15;                // 32x32 tile coords
    const int quad = lane >> 4, m = lane & 15;

    const int ra = ti * 32 + m;                            // + 16 for A1
    const int rb = tj * 32 + m;                            // + 16 for B1
    const float* A0 = ((ra < B) ? (wt + (size_t)ra * D)
                                : (mt + (size_t)(ra - B) * D)) + quad * 8;
    const float* A1 = A0 + (size_t)16 * D;
    const float* B0 = ((rb < B) ? (wt + (size_t)rb * D)
                                : (mt + (size_t)(rb - B) * D)) + quad * 8;
    const float* B1 = B0 + (size_t)16 * D;

    f32x4 acc00 = {0.f, 0.f, 0.f, 0.f};
    f32x4 acc01 = {0.f, 0.f, 0.f, 0.f};
    f32x4 acc10 = {0.f, 0.f, 0.f, 0.f};
    f32x4 acc11 = {0.f, 0.f, 0.f, 0.f};
    #pragma unroll 2
    for (int k0 = 0; k0 < D; k0 += 32) {
        const half8_t a0 = cvt8(A0 + k0);
        const half8_t a1 = cvt8(A1 + k0);
        const half8_t b0 = cvt8(B0 + k0);
        const half8_t b1 = cvt8(B1 + k0);
        acc00 = __builtin_amdgcn_mfma_f32_16x16x32_f16(a0, b0, acc00, 0, 0, 0);
        acc01 = __builtin_amdgcn_mfma_f32_16x16x32_f16(a0, b1, acc01, 0, 0, 0);
        acc10 = __builtin_amdgcn_mfma_f32_16x16x32_f16(a1, b0, acc10, 0, 0, 0);
        acc11 = __builtin_amdgcn_mfma_f32_16x16x32_f16(a1, b1, acc11, 0, 0, 0);
    }
    float* G = ws + WS_G;
    const int r0 = ti * 32 + quad * 4;
    const int c0 = tj * 32 + m;
    #pragma unroll
    for (int rg = 0; rg < 4; ++rg) {
        G[(size_t)(r0 + rg) * N + c0]           = acc00[rg];
        G[(size_t)(r0 + rg) * N + c0 + 16]      = acc01[rg];
        G[(size_t)(r0 + 16 + rg) * N + c0]      = acc10[rg];
        G[(size_t)(r0 + 16 + rg) * N + c0 + 16] = acc11[rg];
    }
}

// ---- kernel 2 (grid 256): block b <-> ORIG rows (2b, 2b+1) ----
__global__ __launch_bounds__(NT) void rnc_main(float* __restrict__ ws)
{
    const int b = blockIdx.x, j0 = 2 * b, j1 = 2 * b + 1;  // ORIG rows
    const int t = threadIdx.x;
    const int w = t >> 6, lane = t & 63;

    __shared__ float sl[N];                    // sorted labels
    __shared__ __align__(16) float sp0[N];
    __shared__ __align__(16) float sf0[N];
    __shared__ __align__(16) float sp1[N];
    __shared__ __align__(16) float sf1[N];
    __shared__ float sred[NT / 64];
    __shared__ int sri[2];

    sl[t] = ws[WS_SL + t];
    const int rk = ((const int*)ws)[WS_RK + t];   // sorted position of orig t
    if (t == j0) sri[0] = rk;
    if (t == j1) sri[1] = rk;

    // ---- phase 1: e from orig-order Gram rows (coalesced) + diag norms ----
    const float* G = ws + WS_G;
    const float g0 = G[(size_t)j0 * N + t];
    const float g1 = G[(size_t)j1 * N + t];
    const float nt = G[(size_t)t * N + t];        // ||f16_t||^2 (MFMA-exact)
    const float n0 = G[(size_t)j0 * N + j0];      // uniform addr -> broadcast
    const float n1 = G[(size_t)j1 * N + j1];
    const float d0 = fmaxf(n0 + nt - 2.f * g0, 0.f);
    const float d1 = fmaxf(n1 + nt - 2.f * g1, 0.f);
    const float lg0 = -0.5f * sqrtf(d0);
    const float lg1 = -0.5f * sqrtf(d1);
    float lg_acc = 0.f;
    if (t != j0) lg_acc += lg0;
    if (t != j1) lg_acc += lg1;
    const float e0 = (t == j0) ? 0.f : __expf(lg0);
    const float e1 = (t == j1) ? 0.f : __expf(lg1);
    sp0[rk] = e0; sf0[rk] = e0;                   // scatter to sorted position
    sp1[rk] = e1; sf1[rk] = e1;
    __syncthreads();

    const int ri0 = sri[0], ri1 = sri[1];         // sorted positions of j0,j1
    const float li0 = sl[ri0], li1 = sl[ri1];

    // ---- phase 2a: wave-parallel scans (unchanged) ----
    if (w < 4) {
        float* arr = (w == 0) ? sp0 : (w == 1) ? sf0 : (w == 2) ? sp1 : sf1;
        float4* a4 = (float4*)arr;
        float4 u0 = a4[lane * 2], u1 = a4[lane * 2 + 1];
        float v0 = u0.x, v1 = u0.y, v2 = u0.z, v3 = u0.w;
        float v4 = u1.x, v5 = u1.y, v6 = u1.z, v7 = u1.w;
        if ((w & 1) == 0) {                    // inclusive prefix scan
            v1 += v0; v2 += v1; v3 += v2; v4 += v3; v5 += v4; v6 += v5; v7 += v6;
            float x = v7;
            #pragma unroll
            for (int off = 1; off < 64; off <<= 1) {
                const float y = __shfl_up(x, off, 64);
                if (lane >= off) x += y;
            }
            float ex = __shfl_up(x, 1, 64);
            if (lane == 0) ex = 0.f;
            v0 += ex; v1 += ex; v2 += ex; v3 += ex; v4 += ex; v5 += ex; v6 += ex; v7 += ex;
        } else {                               // inclusive suffix scan
            v6 += v7; v5 += v6; v4 += v5; v3 += v4; v2 += v3; v1 += v2; v0 += v1;
            float x = v0;
            #pragma unroll
            for (int off = 1; off < 64; off <<= 1) {
                const float y = __shfl_down(x, off, 64);
                if (lane + off < 64) x += y;
            }
            float ex = __shfl_down(x, 1, 64);
            if (lane == 63) ex = 0.f;
            v0 += ex; v1 += ex; v2 += ex; v3 += ex; v4 += ex; v5 += ex; v6 += ex; v7 += ex;
        }
        a4[lane * 2]     = make_float4(v0, v1, v2, v3);
        a4[lane * 2 + 1] = make_float4(v4, v5, v6, v7);
    }
    __syncthreads();

    // ---- phase 2b: per-k denom via two exact binary searches ----
    float local = lg_acc;
    #pragma unroll
    for (int p = 0; p < 2; ++p) {
        const int x = t;                      // this thread's sorted position
        const int ri = p ? ri1 : ri0;
        const float li = p ? li1 : li0;
        const float* SP = p ? sp1 : sp0;
        const float* SF = p ? sf1 : sf0;
        if (x != ri) {
            const float th = fabsf(li - sl[x]);
            int lo = 0, hi = ri + 1;          // left branch: weakly decreasing
            while (lo < hi) {
                const int mid = (lo + hi) >> 1;
                if (fabsf(li - sl[mid]) >= th) lo = mid + 1; else hi = mid;
            }
            const int a = lo;
            lo = ri + 1; hi = N;              // right branch: weakly increasing
            while (lo < hi) {
                const int mid = (lo + hi) >> 1;
                if (fabsf(li - sl[mid]) >= th) hi = mid; else lo = mid + 1;
            }
            const int bb = lo;
            const float denom = ((a > 0) ? SP[a - 1] : 0.f) + ((bb < N) ? SF[bb] : 0.f);
            local -= __logf(denom);
        }
    }

    // ---- block reduction, plain store ----
    #pragma unroll
    for (int off = 32; off > 0; off >>= 1)
        local += __shfl_down(local, off, 64);
    if (lane == 0) sred[w] = local;
    __syncthreads();
    if (t == 0) {
        float sum = 0.f;
        #pragma unroll
        for (int k = 0; k < NT / 64; ++k) sum += sred[k];
        ws[WS_PART + b] = sum;
    }
}

// ---- kernel 3: reduce 256 partials + finalize ----
__global__ __launch_bounds__(NBLK) void rnc_finalize(
    const float* __restrict__ ws, float* __restrict__ out)
{
    const int t = threadIdx.x;
    __shared__ float sred[NBLK / 64];
    float v = ws[WS_PART + t];
    #pragma unroll
    for (int off = 32; off > 0; off >>= 1)
        v += __shfl_down(v, off, 64);
    if ((t & 63) == 0) sred[t >> 6] = v;
    __syncthreads();
    if (t == 0) {
        float sum = 0.f;
        #pragma unroll
        for (int k = 0; k < NBLK / 64; ++k) sum += sred[k];
        out[0] = -sum / (float)((long)N * (N - 1));
    }
}

extern "C" void kernel_launch(void* const* d_in, const int* in_sizes, int n_in,
                              void* d_out, int out_size, void* d_ws, size_t ws_size,
                              hipStream_t stream) {
    const float* wt  = (const float*)d_in[0];
    const float* mt  = (const float*)d_in[1];
    const float* lwt = (const float*)d_in[2];
    const float* lmt = (const float*)d_in[3];
    float* out = (float*)d_out;
    float* ws  = (float*)d_ws;

    gram_kernel<<<33, NT, 0, stream>>>(wt, mt, lwt, lmt, ws);
    rnc_main<<<NBLK, NT, 0, stream>>>(ws);
    rnc_finalize<<<1, NBLK, 0, stream>>>(ws, out);
}

// Round 5
// 75.271 us; speedup vs baseline: 1.2706x; 1.2706x over previous
//
#include <hip/hip_runtime.h>

// R15 — 4 dispatches; main re-split for 2 blocks/CU TLP:
//   sort_rows (128 blk x 512) : ranks + permute rows to sorted fp16 + norms
//                               (verified R12/R13)
//   gram      (64 blk x 256)  : MFMA f16 Gram, 32x32 tile/wave (verified R13)
//   main      (512 blk x 256) : ONE sorted row per block; e from G row, one
//                               prefix + one suffix scan, 2 binsearches/thread.
//                               512 blocks = 2/CU -> cross-block latency hiding
//                               (R13's 256x512 = 1 block/CU had none; main's
//                               interior is latency chains: 18 serial LDS
//                               round-trips/search + serial scans).
// Model recalibration (R12 +8, R14 +19 post-mortems): dispatch gap ~2-4us
// (ticket-fence merge measured +3 net => gaps small); interiors are exposed-
// latency-bound; sort/gram <= 3us each; main ~15-20us dominates.
// Measured regressions to avoid: fused per-block G-rows-in-main (+8us, R12),
// orig-order cvt-in-kernel gram at 33 blk (+19us, R14: serialized L2 latency),
// ticket+threadfence finalize (+3us, R11), permuted-read Gram merge (+5.5us,
// R9), cooperative grid.sync (+90us, R10), fp16 phase-1 in main (+4us, R6).

#define N 512          // n = 2*B
#define B 256
#define D 512
#define NT 512         // block size for sort
#define NBLK 64        // gram blocks

// ws layout (float offsets)
#define WS_SL    0                    // [N] sorted labels ascending
#define WS_NORM  512                  // [N] ||f16||^2 (fp32) by sorted position
#define WS_PART  1024                 // [N] per-block partial sums (512 now)
#define WS_FH    2048                 // N*D _Float16 sorted features (512 KB)
#define WS_G     (2048 + (N * D) / 2) // [N*N] fp32 Gram matrix (1 MB)

typedef _Float16 half4_t  __attribute__((ext_vector_type(4)));
typedef _Float16 half8_t  __attribute__((ext_vector_type(8)));
typedef float    f32x4    __attribute__((ext_vector_type(4)));

// ---- kernel 1 (grid 128): ranks + permute 4 rows/block to sorted fp16 ----
__global__ __launch_bounds__(NT) void sort_rows_kernel(
    const float* __restrict__ wt, const float* __restrict__ mt,
    const float* __restrict__ lwt, const float* __restrict__ lmt,
    float* __restrict__ ws)
{
    const int t = threadIdx.x, b = blockIdx.x;   // b in [0,128)
    __shared__ float slab[N];
    __shared__ int scnt[4];
    __shared__ float swred[NT / 64];
    slab[t] = (t < B) ? lwt[t] : lmt[t - B];
    if (t < 4) scnt[t] = 0;
    __syncthreads();

    const int jj = t >> 7, j = b * 4 + jj;
    const int c = t & 127;
    const float lj = slab[j];
    int r = 0;
    #pragma unroll
    for (int x = c * 4; x < c * 4 + 4; ++x) {
        const float v = slab[x];
        r += (v < lj || (v == lj && x < j)) ? 1 : 0;
    }
    #pragma unroll
    for (int off = 32; off > 0; off >>= 1)
        r += __shfl_down(r, off, 64);
    if ((t & 63) == 0) atomicAdd(&scnt[jj], r);
    __syncthreads();

    if (t < 4)
        ws[WS_SL + scnt[t]] = slab[b * 4 + t];

    const int rr = scnt[jj];                     // sorted position of row j
    const float* F = (j < B) ? (wt + (size_t)j * D) : (mt + (size_t)(j - B) * D);
    const float4 v = ((const float4*)F)[c];
    half4_t h;
    h[0] = (_Float16)v.x; h[1] = (_Float16)v.y;
    h[2] = (_Float16)v.z; h[3] = (_Float16)v.w;
    ((half4_t*)((_Float16*)(ws + WS_FH) + (size_t)rr * D))[c] = h;
    const float f0 = (float)h[0], f1 = (float)h[1];
    const float f2 = (float)h[2], f3 = (float)h[3];
    float nacc = f0 * f0 + f1 * f1 + f2 * f2 + f3 * f3;
    #pragma unroll
    for (int off = 32; off > 0; off >>= 1)
        nacc += __shfl_down(nacc, off, 64);
    if ((t & 63) == 0) swred[t >> 6] = nacc;
    __syncthreads();
    if (t < 4)
        ws[WS_NORM + scnt[t]] = swred[2 * t] + swred[2 * t + 1];
}

// ---- kernel 2 (grid 64 x 256thr): MFMA Gram, 32x32 tile per wave ----
__global__ __launch_bounds__(256) void gram_kernel(float* __restrict__ ws)
{
    const int lane = threadIdx.x & 63;
    const int wid  = blockIdx.x * 4 + (threadIdx.x >> 6);   // 0..255
    const int ti = wid >> 4, tj = wid & 15;                 // 32x32 tile coords
    const int quad = lane >> 4, m = lane & 15;

    const _Float16* Fh = (const _Float16*)(ws + WS_FH);
    const _Float16* A0 = Fh + (size_t)(ti * 32 + m) * D + quad * 8;
    const _Float16* A1 = A0 + (size_t)16 * D;
    const _Float16* B0 = Fh + (size_t)(tj * 32 + m) * D + quad * 8;
    const _Float16* B1 = B0 + (size_t)16 * D;

    f32x4 acc00 = {0.f, 0.f, 0.f, 0.f};
    f32x4 acc01 = {0.f, 0.f, 0.f, 0.f};
    f32x4 acc10 = {0.f, 0.f, 0.f, 0.f};
    f32x4 acc11 = {0.f, 0.f, 0.f, 0.f};
    #pragma unroll
    for (int k0 = 0; k0 < D; k0 += 32) {
        const half8_t a0 = *(const half8_t*)(A0 + k0);
        const half8_t a1 = *(const half8_t*)(A1 + k0);
        const half8_t b0 = *(const half8_t*)(B0 + k0);
        const half8_t b1 = *(const half8_t*)(B1 + k0);
        acc00 = __builtin_amdgcn_mfma_f32_16x16x32_f16(a0, b0, acc00, 0, 0, 0);
        acc01 = __builtin_amdgcn_mfma_f32_16x16x32_f16(a0, b1, acc01, 0, 0, 0);
        acc10 = __builtin_amdgcn_mfma_f32_16x16x32_f16(a1, b0, acc10, 0, 0, 0);
        acc11 = __builtin_amdgcn_mfma_f32_16x16x32_f16(a1, b1, acc11, 0, 0, 0);
    }
    float* G = ws + WS_G;
    const int r0 = ti * 32 + quad * 4;
    const int c0 = tj * 32 + m;
    #pragma unroll
    for (int rg = 0; rg < 4; ++rg) {
        G[(size_t)(r0 + rg) * N + c0]           = acc00[rg];
        G[(size_t)(r0 + rg) * N + c0 + 16]      = acc01[rg];
        G[(size_t)(r0 + 16 + rg) * N + c0]      = acc10[rg];
        G[(size_t)(r0 + 16 + rg) * N + c0 + 16] = acc11[rg];
    }
}

// ---- kernel 3 (grid 512 x 256thr): ONE sorted row per block ----
__global__ __launch_bounds__(256) void rnc_main(float* __restrict__ ws)
{
    const int i = blockIdx.x;                 // sorted position of this row
    const int t = threadIdx.x;                // 0..255
    const int w = t >> 6, lane = t & 63;

    __shared__ float sl[N];
    __shared__ float snm[N];
    __shared__ __align__(16) float sp[N];
    __shared__ __align__(16) float sf[N];
    __shared__ float sred[4];

    sl[t]        = ws[WS_SL + t];
    sl[t + 256]  = ws[WS_SL + t + 256];
    snm[t]       = ws[WS_NORM + t];
    snm[t + 256] = ws[WS_NORM + t + 256];
    __syncthreads();
    const float li = sl[i], ni = snm[i];

    // ---- phase 1: e from precomputed Gram row (coalesced 2 KB) ----
    const float* Grow = ws + WS_G + (size_t)i * N;
    float lg_acc = 0.f;
    #pragma unroll
    for (int q = 0; q < 2; ++q) {
        const int c = t + q * 256;
        const float g = Grow[c];
        const float d = fmaxf(ni + snm[c] - 2.f * g, 0.f);
        const float lg = -0.5f * sqrtf(d);
        const float e = (c == i) ? 0.f : __expf(lg);
        if (c != i) lg_acc += lg;
        sp[c] = e; sf[c] = e;
    }
    __syncthreads();

    // ---- phase 2a: wave 0 prefix-scan sp, wave 1 suffix-scan sf ----
    if (w < 2) {
        float* arr = (w == 0) ? sp : sf;
        float4* a4 = (float4*)arr;
        float4 u0 = a4[lane * 2], u1 = a4[lane * 2 + 1];
        float v0 = u0.x, v1 = u0.y, v2 = u0.z, v3 = u0.w;
        float v4 = u1.x, v5 = u1.y, v6 = u1.z, v7 = u1.w;
        if ((w & 1) == 0) {                    // inclusive prefix scan
            v1 += v0; v2 += v1; v3 += v2; v4 += v3; v5 += v4; v6 += v5; v7 += v6;
            float x = v7;
            #pragma unroll
            for (int off = 1; off < 64; off <<= 1) {
                const float y = __shfl_up(x, off, 64);
                if (lane >= off) x += y;
            }
            float ex = __shfl_up(x, 1, 64);
            if (lane == 0) ex = 0.f;
            v0 += ex; v1 += ex; v2 += ex; v3 += ex; v4 += ex; v5 += ex; v6 += ex; v7 += ex;
        } else {                               // inclusive suffix scan
            v6 += v7; v5 += v6; v4 += v5; v3 += v4; v2 += v3; v1 += v2; v0 += v1;
            float x = v0;
            #pragma unroll
            for (int off = 1; off < 64; off <<= 1) {
                const float y = __shfl_down(x, off, 64);
                if (lane + off < 64) x += y;
            }
            float ex = __shfl_down(x, 1, 64);
            if (lane == 63) ex = 0.f;
            v0 += ex; v1 += ex; v2 += ex; v3 += ex; v4 += ex; v5 += ex; v6 += ex; v7 += ex;
        }
        a4[lane * 2]     = make_float4(v0, v1, v2, v3);
        a4[lane * 2 + 1] = make_float4(v4, v5, v6, v7);
    }
    __syncthreads();

    // ---- phase 2b: two binsearches per thread (cols t, t+256), ri == i ----
    float local = lg_acc;
    #pragma unroll
    for (int q = 0; q < 2; ++q) {
        const int x = t + q * 256;            // sorted position of k
        if (x != i) {
            const float th = fabsf(li - sl[x]);
            int lo = 0, hi = i + 1;           // left branch: weakly decreasing
            while (lo < hi) {
                const int mid = (lo + hi) >> 1;
                if (fabsf(li - sl[mid]) >= th) lo = mid + 1; else hi = mid;
            }
            const int a = lo;
            lo = i + 1; hi = N;               // right branch: weakly increasing
            while (lo < hi) {
                const int mid = (lo + hi) >> 1;
                if (fabsf(li - sl[mid]) >= th) hi = mid; else lo = mid + 1;
            }
            const int bb = lo;
            const float denom = ((a > 0) ? sp[a - 1] : 0.f) + ((bb < N) ? sf[bb] : 0.f);
            local -= __logf(denom);
        }
    }

    // ---- block reduction (4 waves), plain store ----
    #pragma unroll
    for (int off = 32; off > 0; off >>= 1)
        local += __shfl_down(local, off, 64);
    if (lane == 0) sred[w] = local;
    __syncthreads();
    if (t == 0) {
        float sum = 0.f;
        #pragma unroll
        for (int k = 0; k < 4; ++k) sum += sred[k];
        ws[WS_PART + i] = sum;
    }
}

// ---- kernel 4: reduce 512 partials + finalize ----
__global__ __launch_bounds__(N) void rnc_finalize(
    const float* __restrict__ ws, float* __restrict__ out)
{
    const int t = threadIdx.x;
    __shared__ float sred[N / 64];
    float v = ws[WS_PART + t];
    #pragma unroll
    for (int off = 32; off > 0; off >>= 1)
        v += __shfl_down(v, off, 64);
    if ((t & 63) == 0) sred[t >> 6] = v;
    __syncthreads();
    if (t == 0) {
        float sum = 0.f;
        #pragma unroll
        for (int k = 0; k < N / 64; ++k) sum += sred[k];
        out[0] = -sum / (float)((long)N * (N - 1));
    }
}

extern "C" void kernel_launch(void* const* d_in, const int* in_sizes, int n_in,
                              void* d_out, int out_size, void* d_ws, size_t ws_size,
                              hipStream_t stream) {
    const float* wt  = (const float*)d_in[0];
    const float* mt  = (const float*)d_in[1];
    const float* lwt = (const float*)d_in[2];
    const float* lmt = (const float*)d_in[3];
    float* out = (float*)d_out;
    float* ws  = (float*)d_ws;

    sort_rows_kernel<<<128, NT, 0, stream>>>(wt, mt, lwt, lmt, ws);
    gram_kernel<<<NBLK, 256, 0, stream>>>(ws);
    rnc_main<<<N, 256, 0, stream>>>(ws);
    rnc_finalize<<<1, N, 0, stream>>>(ws, out);
}